// Round 13
// baseline (1290.243 us; speedup 1.0000x reference)
//
#include <hip/hip_runtime.h>

#define BB   2048
#define NNX  64
#define DD   256
#define KKC  32
#define LLN  2
#define HHN  8
#define DHH  32
#define DFFN 1024
#define BNT  (BB*NNX)   // 131072

typedef short s16x8 __attribute__((ext_vector_type(8)));
typedef float f32x4 __attribute__((ext_vector_type(4)));

#define GLOAD_LDS16(gp, lp) __builtin_amdgcn_global_load_lds( \
    (const __attribute__((address_space(1))) void*)(gp),      \
    (__attribute__((address_space(3))) void*)(lp), 16, 0, 0)

#define WAITVM4() asm volatile("s_waitcnt vmcnt(4)" ::: "memory")
#define WAITVM0() asm volatile("s_waitcnt vmcnt(0)" ::: "memory")
#define WAITLGKM0() do { asm volatile("s_waitcnt lgkmcnt(0)" ::: "memory"); \
                         __builtin_amdgcn_sched_barrier(0); } while (0)
#define SBAR() __builtin_amdgcn_s_barrier()

__device__ __forceinline__ unsigned short f2bf(float f) {
  unsigned int u = __float_as_uint(f);
  u += 0x7fffu + ((u >> 16) & 1u);   // RNE
  return (unsigned short)(u >> 16);
}
__device__ __forceinline__ float bf2f(unsigned short u) {
  return __uint_as_float(((unsigned int)u) << 16);
}

// ---------------- f32 -> bf16 bulk convert (input) ----------------
__global__ __launch_bounds__(256) void cvt_kernel(const float4* __restrict__ src,
                                                  ushort4* __restrict__ dst, int n4) {
  int i = blockIdx.x * 256 + threadIdx.x;
  int st = gridDim.x * 256;
  for (; i < n4; i += st) {
    float4 v = src[i];
    ushort4 o;
    o.x = f2bf(v.x); o.y = f2bf(v.y); o.z = f2bf(v.z); o.w = f2bf(v.w);
    dst[i] = o;
  }
}

// ---------------- all-weights f32 -> bf16 in one launch ----------------
__global__ __launch_bounds__(256) void cvtw_kernel(const float4* __restrict__ wq, ushort4* __restrict__ dq,
                                                   const float4* __restrict__ wo, ushort4* __restrict__ dov,
                                                   const float4* __restrict__ w1, ushort4* __restrict__ d1,
                                                   const float4* __restrict__ w2, ushort4* __restrict__ d2) {
  const int n0 = 98304, n1 = 32768, n2 = 131072, n3 = 131072;  // float4 counts
  int i = blockIdx.x * 256 + threadIdx.x;
  int st = gridDim.x * 256;
  for (; i < n0 + n1 + n2 + n3; i += st) {
    const float4* s; ushort4* d; int j = i;
    if (j < n0) { s = wq; d = dq; }
    else if ((j -= n0) < n1) { s = wo; d = dov; }
    else if ((j -= n1) < n2) { s = w1; d = d1; }
    else { j -= n2; s = w2; d = d2; }
    float4 v = s[j];
    ushort4 o;
    o.x = f2bf(v.x); o.y = f2bf(v.y); o.z = f2bf(v.z); o.w = f2bf(v.w);
    d[j] = o;
  }
}

// -------- tanh(mu) table: bf16 [32][264] (padded) + |mt|^2 f32 --------
__global__ void mt_kernel(const float* __restrict__ mus, unsigned short* __restrict__ mtb,
                          float* __restrict__ mtn) {
  int k = threadIdx.x;
  if (k < 32) {
    float acc = 0.f;
    for (int d = 0; d < 256; d++) {
      float t = tanhf(mus[k * 256 + d]);
      mtb[k * 264 + d] = f2bf(t);
      acc += t * t;
    }
    mtn[k] = acc;
  }
}

// ---------------- prob_pi, prob_A, zero entropy ----------------
__global__ void piA_kernel(const float* __restrict__ il, const float* __restrict__ tl,
                           float* __restrict__ d_pi, float* __restrict__ d_A,
                           float* __restrict__ d_ent) {
  int lane = threadIdx.x;
  if (lane == 0) *d_ent = 0.f;
  if (lane < 32) {
    float v = il[lane];
    float mx = v;
    #pragma unroll
    for (int off = 16; off; off >>= 1) mx = fmaxf(mx, __shfl_xor(mx, off, 32));
    float e = expf(v - mx), sm = e;
    #pragma unroll
    for (int off = 16; off; off >>= 1) sm += __shfl_xor(sm, off, 32);
    d_pi[lane] = e / sm;
    for (int r = 0; r < 32; r++) {
      float a = tl[r * 32 + lane];
      float m2 = a;
      #pragma unroll
      for (int off = 16; off; off >>= 1) m2 = fmaxf(m2, __shfl_xor(m2, off, 32));
      float e2 = expf(a - m2), s2 = e2;
      #pragma unroll
      for (int off = 16; off; off >>= 1) s2 += __shfl_xor(s2, off, 32);
      d_A[r * 32 + lane] = e2 / s2;
    }
  }
}

// ======== 128x128 tile, BK=32, 4-wave, counted-vmcnt pipelined NT GEMM ========
// (R7-proven structure) EPI 0: bf16 out; 1: relu->bf16; 2: +res(bf16)->bf16.
template <int EPI>
__global__ __launch_bounds__(256, 4) void gemm_nt(const unsigned short* __restrict__ A,
                                                  const unsigned short* __restrict__ Bw,
                                                  const float* __restrict__ bias,
                                                  const unsigned short* __restrict__ res,
                                                  unsigned short* __restrict__ outp,
                                                  int N, int K, int nx) {
  __shared__ unsigned short lds[16384];   // 32 KB: [2 buf][A 4096 | B 4096]
  const int t = threadIdx.x;
  const int bid = blockIdx.x, nwg = gridDim.x;
  const int wg = (bid & 7) * (nwg >> 3) + (bid >> 3);   // nwg % 8 == 0
  const int m0 = (wg / nx) << 7;
  const int n0 = (wg % nx) << 7;
  const int lane = t & 63, w = t >> 6;
  const int wm = w >> 1, wn = w & 1;      // 2x2 waves, wave tile 64x64
  const int lr = lane & 15, lk = lane >> 4;

  const int r0 = t >> 2, sg = t & 3;
  const int s0 = sg ^ ((r0 >> 1) & 3);
  const int r1 = r0 + 64;
  const int s1 = sg ^ ((r1 >> 1) & 3);
  const int aoff0 = (m0 + r0) * K + s0 * 8;
  const int aoff1 = (m0 + r1) * K + s1 * 8;
  const int boff0 = (n0 + r0) * K + s0 * 8;
  const int boff1 = (n0 + r1) * K + s1 * 8;

#define STAGE(buf, k0) do {                                    \
    char* la = (char*)lds + (buf) * 16384;                     \
    GLOAD_LDS16(A + aoff0 + (k0), la + t * 16);                \
    GLOAD_LDS16(A + aoff1 + (k0), la + 4096 + t * 16);         \
    GLOAD_LDS16(Bw + boff0 + (k0), la + 8192 + t * 16);        \
    GLOAD_LDS16(Bw + boff1 + (k0), la + 12288 + t * 16);       \
  } while (0)

  f32x4 acc[4][4];
  #pragma unroll
  for (int i = 0; i < 4; i++)
    #pragma unroll
    for (int j = 0; j < 4; j++) acc[i][j] = (f32x4)(0.f);

  const int ra = wm * 64 + lr, rb = wn * 64 + lr;
  const int sla = lk ^ ((ra >> 1) & 3), slb = lk ^ ((rb >> 1) & 3);

  const int NT = K >> 5;
  STAGE(0, 0);
  STAGE(1, 32);
  WAITVM4();
  SBAR();

  int c = 0;
  for (int kt = 0; kt < NT; kt++) {
    s16x8 af[4], bf[4];
    {
      const unsigned short* ua = lds + c * 8192;
      const unsigned short* ub = ua + 4096;
      #pragma unroll
      for (int mf = 0; mf < 4; mf++)
        af[mf] = *(const s16x8*)&ua[(ra + mf * 16) * 32 + sla * 8];
      #pragma unroll
      for (int nf = 0; nf < 4; nf++)
        bf[nf] = *(const s16x8*)&ub[(rb + nf * 16) * 32 + slb * 8];
    }
    __builtin_amdgcn_s_setprio(1);
    #pragma unroll
    for (int mf = 0; mf < 4; mf++)
      #pragma unroll
      for (int nf = 0; nf < 4; nf++)
        acc[mf][nf] = __builtin_amdgcn_mfma_f32_16x16x32_bf16(af[mf], bf[nf], acc[mf][nf], 0, 0, 0);
    __builtin_amdgcn_s_setprio(0);
    SBAR();
    if (kt < NT - 2) {
      STAGE(c, (kt + 2) << 5);
      WAITVM4();
    } else if (kt == NT - 2) {
      WAITVM0();
    }
    SBAR();
    c ^= 1;
  }
#undef STAGE

  #pragma unroll
  for (int nf = 0; nf < 4; nf++) {
    int col = n0 + wn * 64 + nf * 16 + lr;
    float bv = bias[col];
    #pragma unroll
    for (int mf = 0; mf < 4; mf++)
      #pragma unroll
      for (int r = 0; r < 4; r++) {
        int row = m0 + wm * 64 + mf * 16 + lk * 4 + r;
        size_t o = (size_t)row * N + col;
        float v = acc[mf][nf][r] + bv;
        if (EPI == 1) v = fmaxf(v, 0.f);
        if (EPI == 2) v += bf2f(res[o]);
        outp[o] = f2bf(v);
      }
  }
}

// ------- GEMM (BM=128, BN=256 full width) + bias + residual + LayerNorm -------
// (R4-measured version; kept for the Wo projection, K=256)
template <bool WR32>
__global__ __launch_bounds__(512) void gemm_ln(const unsigned short* __restrict__ A,
                                               const unsigned short* __restrict__ Bw,
                                               const float* __restrict__ bias,
                                               const unsigned short* __restrict__ res,
                                               const float* __restrict__ g,
                                               const float* __restrict__ bta,
                                               unsigned short* __restrict__ xb,
                                               float* __restrict__ x32,
                                               int K) {
  __shared__ unsigned short As[128 * 64];
  __shared__ unsigned short Bs[256 * 64];
  __shared__ float stats[2][128][4];
  const int t = threadIdx.x;
  const int nwg = gridDim.x;
  const int bid = blockIdx.x;
  const int wg = (bid & 7) * (nwg >> 3) + (bid >> 3);
  const int m0 = wg << 7;

  const int lane = t & 63, w = t >> 6;
  const int wm = w >> 2, wn = w & 3;
  const int lr = lane & 15, lk = lane >> 4;

  size_t aoff[2], boff[4];
  #pragma unroll
  for (int p = 0; p < 2; p++) {
    int u = p * 512 + t;
    int row = u >> 3, sp = u & 7;
    int seg = sp ^ (((row >> 2) & 1) << 1);
    aoff[p] = (size_t)(m0 + row) * K + seg * 8;
  }
  #pragma unroll
  for (int p = 0; p < 4; p++) {
    int u = p * 512 + t;
    int row = u >> 3, sp = u & 7;
    int seg = sp ^ (((row >> 2) & 1) << 1);
    boff[p] = (size_t)row * K + seg * 8;
  }

  f32x4 acc[4][4];
  #pragma unroll
  for (int i = 0; i < 4; i++)
    #pragma unroll
    for (int j = 0; j < 4; j++) acc[i][j] = (f32x4)(0.f);

  for (int k0 = 0; k0 < K; k0 += 64) {
    #pragma unroll
    for (int p = 0; p < 2; p++)
      GLOAD_LDS16(A + aoff[p] + k0, (char*)As + (p * 512 + t) * 16);
    #pragma unroll
    for (int p = 0; p < 4; p++)
      GLOAD_LDS16(Bw + boff[p] + k0, (char*)Bs + (p * 512 + t) * 16);
    __syncthreads();
    #pragma unroll
    for (int z = 0; z < 2; z++) {
      s16x8 af[4], bfr[4];
      #pragma unroll
      for (int mf = 0; mf < 4; mf++) {
        int row = wm * 64 + mf * 16 + lr;
        int cc = (z * 4 + lk) ^ (((row >> 2) & 1) << 1);
        af[mf] = *(const s16x8*)&As[row * 64 + cc * 8];
      }
      #pragma unroll
      for (int nf = 0; nf < 4; nf++) {
        int row = wn * 64 + nf * 16 + lr;
        int cc = (z * 4 + lk) ^ (((row >> 2) & 1) << 1);
        bfr[nf] = *(const s16x8*)&Bs[row * 64 + cc * 8];
      }
      #pragma unroll
      for (int mf = 0; mf < 4; mf++)
        #pragma unroll
        for (int nf = 0; nf < 4; nf++)
          acc[mf][nf] = __builtin_amdgcn_mfma_f32_16x16x32_bf16(af[mf], bfr[nf], acc[mf][nf], 0, 0, 0);
    }
    __syncthreads();
  }

  float bv[4];
  #pragma unroll
  for (int nf = 0; nf < 4; nf++) bv[nf] = bias[wn * 64 + nf * 16 + lr];

  #pragma unroll
  for (int mf = 0; mf < 4; mf++) {
    #pragma unroll
    for (int r = 0; r < 4; r++) {
      int grow = m0 + wm * 64 + mf * 16 + lk * 4 + r;
      float s = 0.f, q = 0.f;
      #pragma unroll
      for (int nf = 0; nf < 4; nf++) {
        int col = wn * 64 + nf * 16 + lr;
        float v = acc[mf][nf][r] + bv[nf] + bf2f(res[(size_t)grow * 256 + col]);
        acc[mf][nf][r] = v;
        s += v; q += v * v;
      }
      #pragma unroll
      for (int off = 1; off < 16; off <<= 1) { s += __shfl_xor(s, off); q += __shfl_xor(q, off); }
      if (lr == 0) {
        int lrow = wm * 64 + mf * 16 + lk * 4 + r;
        stats[0][lrow][wn] = s;
        stats[1][lrow][wn] = q;
      }
    }
  }
  __syncthreads();

  float gv[4], bbv[4];
  #pragma unroll
  for (int nf = 0; nf < 4; nf++) {
    int col = wn * 64 + nf * 16 + lr;
    gv[nf] = g[col]; bbv[nf] = bta[col];
  }
  #pragma unroll
  for (int mf = 0; mf < 4; mf++) {
    #pragma unroll
    for (int r = 0; r < 4; r++) {
      int lrow = wm * 64 + mf * 16 + lk * 4 + r;
      int grow = m0 + lrow;
      float s4 = stats[0][lrow][0] + stats[0][lrow][1] + stats[0][lrow][2] + stats[0][lrow][3];
      float q4 = stats[1][lrow][0] + stats[1][lrow][1] + stats[1][lrow][2] + stats[1][lrow][3];
      float mean = s4 * (1.f / 256.f);
      float var = q4 * (1.f / 256.f) - mean * mean;
      float rs = rsqrtf(var + 1e-5f);
      #pragma unroll
      for (int nf = 0; nf < 4; nf++) {
        int col = wn * 64 + nf * 16 + lr;
        float val = (acc[mf][nf][r] - mean) * rs * gv[nf] + bbv[nf];
        xb[(size_t)grow * 256 + col] = f2bf(val);
        if (WR32) x32[(size_t)grow * 256 + col] = val;
      }
    }
  }
}

// ---------------- standalone LayerNorm: one wave per token, bf16 in ----------
// (R2-measured ~5 TB/s). Writes xb bf16; WR32 also writes f32 x (final layer).
template <bool WR32>
__global__ __launch_bounds__(256) void ln_kernel(const unsigned short* __restrict__ yin,
                                                 const float* __restrict__ g,
                                                 const float* __restrict__ bta,
                                                 unsigned short* __restrict__ xb,
                                                 float* __restrict__ xout) {
  const int w = threadIdx.x >> 6, lane = threadIdx.x & 63;
  const size_t tok = (size_t)blockIdx.x * 4 + w;
  ushort4 u = *((const ushort4*)(yin + tok * 256) + lane);
  float v[4] = {bf2f(u.x), bf2f(u.y), bf2f(u.z), bf2f(u.w)};
  float s = v[0] + v[1] + v[2] + v[3];
  float q = v[0] * v[0] + v[1] * v[1] + v[2] * v[2] + v[3] * v[3];
  #pragma unroll
  for (int off = 1; off < 64; off <<= 1) { s += __shfl_xor(s, off); q += __shfl_xor(q, off); }
  float mean = s * (1.f / 256.f);
  float var = q * (1.f / 256.f) - mean * mean;
  float rs = rsqrtf(var + 1e-5f);
  int d0 = lane * 4;
  float o0 = (v[0] - mean) * rs * g[d0 + 0] + bta[d0 + 0];
  float o1 = (v[1] - mean) * rs * g[d0 + 1] + bta[d0 + 1];
  float o2 = (v[2] - mean) * rs * g[d0 + 2] + bta[d0 + 2];
  float o3 = (v[3] - mean) * rs * g[d0 + 3] + bta[d0 + 3];
  ushort4 ub = {f2bf(o0), f2bf(o1), f2bf(o2), f2bf(o3)};
  *((ushort4*)(xb + tok * 256) + lane) = ub;
  if (WR32) {
    float4 fo = {o0, o1, o2, o3};
    *((float4*)(xout + tok * 256) + lane) = fo;
  }
}

// ---------------- attention: one wave per (b,h), compact LDS, V^T ----------
// (R11-proven, unchanged)
__global__ __launch_bounds__(64) void attn_kernel(const unsigned short* __restrict__ qkv,
                                                  unsigned short* __restrict__ ob) {
  __shared__ unsigned short al[6784];   // 13568 B
  unsigned short* qs = al;              // shorts [0,2048)
  unsigned short* ks = al + 2048;       // shorts [2048,4096)
  unsigned short* vs = al + 4608;       // shorts [4608,6656)
  unsigned short* vt = al;              // shorts [0,2176)   = [32][68]
  unsigned short* ps = al + 2176;       // shorts [2176,6784) = [64][72]
  const int bh = blockIdx.x;
  const int b = bh >> 3, h = bh & 7;
  const int lane = threadIdx.x;
  const int lr = lane & 15, lk = lane >> 4;

  #pragma unroll
  for (int p = 0; p < 4; p++) {
    int u = lane + p * 64;
    int row = u >> 2, seg = u & 3;
    size_t gb = (size_t)(b * 64 + row) * 768 + h * 32 + seg * 8;
    GLOAD_LDS16(qkv + gb, (char*)al + u * 16);
    GLOAD_LDS16(qkv + gb + 256, (char*)al + 4096 + u * 16);
    GLOAD_LDS16(qkv + gb + 512, (char*)al + 9216 + u * 16);
  }
  __syncthreads();

  s16x8 aq[4], bk[4], vchunk[4];
  #pragma unroll
  for (int mi = 0; mi < 4; mi++) aq[mi] = *(const s16x8*)&qs[(mi * 16 + lr) * 32 + lk * 8];
  #pragma unroll
  for (int nj = 0; nj < 4; nj++) bk[nj] = *(const s16x8*)&ks[(nj * 16 + lr) * 32 + lk * 8];
  const int vrow = lane >> 2, vcs = (lane & 3) * 8;
  #pragma unroll
  for (int q = 0; q < 4; q++)
    vchunk[q] = *(const s16x8*)&vs[(q * 16 + vrow) * 32 + vcs];
  WAITLGKM0();

  #pragma unroll
  for (int q = 0; q < 4; q++)
    #pragma unroll
    for (int j = 0; j < 8; j++)
      vt[(vcs + j) * 68 + q * 16 + vrow] = (unsigned short)vchunk[q][j];

  f32x4 s[4][4];
  #pragma unroll
  for (int i = 0; i < 4; i++)
    #pragma unroll
    for (int j = 0; j < 4; j++) s[i][j] = (f32x4)(0.f);
  #pragma unroll
  for (int mi = 0; mi < 4; mi++)
    #pragma unroll
    for (int nj = 0; nj < 4; nj++)
      s[mi][nj] = __builtin_amdgcn_mfma_f32_16x16x32_bf16(aq[mi], bk[nj], s[mi][nj], 0, 0, 0);

  const float scale = 0.17677669529663687f;
  #pragma unroll
  for (int mi = 0; mi < 4; mi++) {
    #pragma unroll
    for (int r = 0; r < 4; r++) {
      float t0 = s[mi][0][r] * scale, t1 = s[mi][1][r] * scale;
      float t2 = s[mi][2][r] * scale, t3 = s[mi][3][r] * scale;
      float mx = fmaxf(fmaxf(t0, t1), fmaxf(t2, t3));
      #pragma unroll
      for (int off = 8; off; off >>= 1) mx = fmaxf(mx, __shfl_xor(mx, off, 16));
      float e0 = expf(t0 - mx), e1 = expf(t1 - mx), e2 = expf(t2 - mx), e3 = expf(t3 - mx);
      float sm = e0 + e1 + e2 + e3;
      #pragma unroll
      for (int off = 8; off; off >>= 1) sm += __shfl_xor(sm, off, 16);
      float inv = 1.f / sm;
      int prow = mi * 16 + lk * 4 + r;
      ps[prow * 72 + lr + 0]  = f2bf(e0 * inv);
      ps[prow * 72 + lr + 16] = f2bf(e1 * inv);
      ps[prow * 72 + lr + 32] = f2bf(e2 * inv);
      ps[prow * 72 + lr + 48] = f2bf(e3 * inv);
    }
  }
  WAITLGKM0();

  f32x4 oacc[4][2];
  #pragma unroll
  for (int i = 0; i < 4; i++) { oacc[i][0] = (f32x4)(0.f); oacc[i][1] = (f32x4)(0.f); }
  #pragma unroll
  for (int kk = 0; kk < 2; kk++) {
    s16x8 bv[2];
    #pragma unroll
    for (int nf = 0; nf < 2; nf++)
      bv[nf] = *(const s16x8*)&vt[(nf * 16 + lr) * 68 + kk * 32 + lk * 8];
    #pragma unroll
    for (int mi = 0; mi < 4; mi++) {
      s16x8 ap = *(const s16x8*)&ps[(mi * 16 + lr) * 72 + kk * 32 + lk * 8];
      #pragma unroll
      for (int nf = 0; nf < 2; nf++)
        oacc[mi][nf] = __builtin_amdgcn_mfma_f32_16x16x32_bf16(ap, bv[nf], oacc[mi][nf], 0, 0, 0);
    }
  }
  #pragma unroll
  for (int mi = 0; mi < 4; mi++)
    #pragma unroll
    for (int nf = 0; nf < 2; nf++)
      #pragma unroll
      for (int r = 0; r < 4; r++) {
        int tok = mi * 16 + lk * 4 + r;
        int c = nf * 16 + lr;
        ob[(size_t)(b * 64 + tok) * 256 + h * 32 + c] = f2bf(oacc[mi][nf][r]);
      }
}

// -------- cluster probs -> log_emit via MFMA (R12-proven, unchanged) --------
__global__ __launch_bounds__(256) void cluster_kernel(const unsigned short* __restrict__ xb,
                                                      const unsigned short* __restrict__ mtb,
                                                      const float* __restrict__ mtn,
                                                      float* __restrict__ log_emit) {
  __shared__ unsigned short ms[32 * 264];   // 16.5 KB
  const int t = threadIdx.x;
  for (int i = t; i < 2112; i += 256)
    ((uint2*)ms)[i] = ((const uint2*)mtb)[i];
  const int lane = t & 63, w = t >> 6;
  const int lr = lane & 15, lk = lane >> 4;
  const float mtn0 = mtn[lr], mtn1 = mtn[16 + lr];
  __syncthreads();

  const size_t tok0 = (size_t)blockIdx.x * 256 + (size_t)w * 64;
  f32x4 s[4][2];
  #pragma unroll
  for (int i = 0; i < 4; i++) { s[i][0] = (f32x4)(0.f); s[i][1] = (f32x4)(0.f); }

  #pragma unroll
  for (int kk = 0; kk < 8; kk++) {
    s16x8 bf0 = *(const s16x8*)&ms[lr * 264 + lk * 8 + kk * 32];
    s16x8 bf1 = *(const s16x8*)&ms[(16 + lr) * 264 + lk * 8 + kk * 32];
    #pragma unroll
    for (int mi = 0; mi < 4; mi++) {
      s16x8 af = *(const s16x8*)&xb[(tok0 + mi * 16 + lr) * 256 + lk * 8 + kk * 32];
      s[mi][0] = __builtin_amdgcn_mfma_f32_16x16x32_bf16(af, bf0, s[mi][0], 0, 0, 0);
      s[mi][1] = __builtin_amdgcn_mfma_f32_16x16x32_bf16(af, bf1, s[mi][1], 0, 0, 0);
    }
  }

  #pragma unroll
  for (int mi = 0; mi < 4; mi++) {
    #pragma unroll
    for (int r = 0; r < 4; r++) {
      float l0 = (2.f * s[mi][0][r] - mtn0) * 0.1f;
      float l1 = (2.f * s[mi][1][r] - mtn1) * 0.1f;
      float mx = fmaxf(l0, l1);
      #pragma unroll
      for (int off = 8; off; off >>= 1) mx = fmaxf(mx, __shfl_xor(mx, off, 16));
      float e0 = expf(l0 - mx), e1 = expf(l1 - mx);
      float sm = e0 + e1;
      #pragma unroll
      for (int off = 8; off; off >>= 1) sm += __shfl_xor(sm, off, 16);
      float inv = 1.f / sm;
      size_t row = tok0 + mi * 16 + lk * 4 + r;
      log_emit[row * 32 + lr]      = logf(e0 * inv + 1e-10f);
      log_emit[row * 32 + 16 + lr] = logf(e1 * inv + 1e-10f);
    }
  }
}

// ---------------- HMM forward scan + entropy ----------------
__global__ __launch_bounds__(256) void scan_kernel(const float* __restrict__ log_emit,
                                                   const float* __restrict__ pi,
                                                   const float* __restrict__ A,
                                                   float* __restrict__ cp,
                                                   float* __restrict__ ent) {
  const int g = threadIdx.x >> 5, j = threadIdx.x & 31;
  const int batch = blockIdx.x * 8 + g;
  float regA[32];
  #pragma unroll
  for (int i = 0; i < 32; i++) regA[i] = A[i * 32 + j];
  const float* le = log_emit + (size_t)batch * 64 * 32;
  float* cpo = cp + (size_t)batch * 64 * 32;

  float u = logf(pi[j] + 1e-10f) + le[j];
  float mx = u;
  #pragma unroll
  for (int off = 16; off; off >>= 1) mx = fmaxf(mx, __shfl_xor(mx, off, 32));
  float e = expf(u - mx), sm = e;
  #pragma unroll
  for (int off = 16; off; off >>= 1) sm += __shfl_xor(sm, off, 32);
  float p = e / sm;
  cpo[j] = p;
  float enta = p * logf(p + 1e-10f);

  for (int n = 1; n < 64; n++) {
    float tt = 0.f;
    #pragma unroll
    for (int i = 0; i < 32; i++) tt += __shfl(p, i, 32) * regA[i];
    u = logf(tt + 1e-10f) + le[n * 32 + j];
    mx = u;
    #pragma unroll
    for (int off = 16; off; off >>= 1) mx = fmaxf(mx, __shfl_xor(mx, off, 32));
    e = expf(u - mx); sm = e;
    #pragma unroll
    for (int off = 16; off; off >>= 1) sm += __shfl_xor(sm, off, 32);
    p = e / sm;
    cpo[n * 32 + j] = p;
    enta += p * logf(p + 1e-10f);
  }
  #pragma unroll
  for (int off = 16; off; off >>= 1) enta += __shfl_xor(enta, off, 32);
  if (j == 0) atomicAdd(ent, -enta * (1.f / (2048.f * 64.f)));
}

// ---------------- launcher ----------------
extern "C" void kernel_launch(void* const* d_in, const int* in_sizes, int n_in,
                              void* d_out, int out_size, void* d_ws, size_t ws_size,
                              hipStream_t stream) {
  const float* input = (const float*)d_in[0];
  const float* init_logits = (const float*)d_in[1];
  const float* trans = (const float*)d_in[2];
  const float* Wqkv = (const float*)d_in[3];
  const float* bqkv = (const float*)d_in[4];
  const float* Wo = (const float*)d_in[5];
  const float* bo = (const float*)d_in[6];
  const float* ln1g = (const float*)d_in[7];
  const float* ln1b = (const float*)d_in[8];
  const float* ln2g = (const float*)d_in[9];
  const float* ln2b = (const float*)d_in[10];
  const float* W1 = (const float*)d_in[11];
  const float* b1 = (const float*)d_in[12];
  const float* W2 = (const float*)d_in[13];
  const float* b2 = (const float*)d_in[14];
  const float* mus = (const float*)d_in[15];

  float* out = (float*)d_out;
  float* cp = out;                  // [BN,32]
  float* x = out + 4194304;         // emb_all [BN,256] f32
  float* d_pi = out + 37748736;
  float* d_A = out + 37748768;
  float* d_ent = out + 37749792;

  char* ws = (char*)d_ws;
  unsigned short* qkv = (unsigned short*)ws;        // region A: qkv -> hb -> log_emit
  unsigned short* hb = (unsigned short*)ws;
  float* log_emit = (float*)ws;
  unsigned short* ob = (unsigned short*)(ws + 268435456ull);   // region B: attn out / y2
  unsigned short* y2 = ob;
  unsigned short* xb = (unsigned short*)(ws + 335544320ull);   // residual stream bf16
  unsigned short* wq_b = (unsigned short*)(ws + 402653184ull);
  unsigned short* wo_b = (unsigned short*)(ws + 402653184ull + 786432ull);
  unsigned short* w1_b = (unsigned short*)(ws + 402653184ull + 1048576ull);
  unsigned short* w2_b = (unsigned short*)(ws + 402653184ull + 2097152ull);
  unsigned short* mtb = (unsigned short*)(ws + 402653184ull + 3145728ull);  // [32][264] bf16
  float* mtn = (float*)(ws + 402653184ull + 3178496ull);

  cvt_kernel<<<2048, 256, 0, stream>>>((const float4*)input, (ushort4*)xb, BNT * 256 / 4);
  cvtw_kernel<<<512, 256, 0, stream>>>((const float4*)Wqkv, (ushort4*)wq_b,
                                       (const float4*)Wo, (ushort4*)wo_b,
                                       (const float4*)W1, (ushort4*)w1_b,
                                       (const float4*)W2, (ushort4*)w2_b);
  mt_kernel<<<1, 64, 0, stream>>>(mus, mtb, mtn);
  piA_kernel<<<1, 64, 0, stream>>>(init_logits, trans, d_pi, d_A, d_ent);

  for (int l = 0; l < 2; l++) {
    gemm_nt<0><<<6144, 256, 0, stream>>>(xb, wq_b + l * 196608, bqkv + l * 768,
                                         nullptr, qkv, 768, 256, 6);
    attn_kernel<<<16384, 64, 0, stream>>>(qkv, ob);
    gemm_ln<false><<<1024, 512, 0, stream>>>(ob, wo_b + l * 65536, bo + l * 256,
                                             xb, ln1g + l * 256, ln1b + l * 256,
                                             xb, nullptr, 256);
    gemm_nt<1><<<8192, 256, 0, stream>>>(xb, w1_b + l * 262144, b1 + l * 1024,
                                         nullptr, hb, 1024, 256, 8);
    // FFN2: pipelined gemm (+bias +residual) -> y2, then standalone LN
    gemm_nt<2><<<2048, 256, 0, stream>>>(hb, w2_b + l * 262144, b2 + l * 256,
                                         xb, y2, 256, 1024, 2);
    if (l == LLN - 1)
      ln_kernel<true><<<32768, 256, 0, stream>>>(y2, ln2g + l * 256, ln2b + l * 256, xb, x);
    else
      ln_kernel<false><<<32768, 256, 0, stream>>>(y2, ln2g + l * 256, ln2b + l * 256, xb, nullptr);
  }

  cluster_kernel<<<512, 256, 0, stream>>>(xb, mtb, mtn, log_emit);
  scan_kernel<<<256, 256, 0, stream>>>(log_emit, d_pi, d_A, cp, d_ent);
}

// Round 15
// 1110.895 us; speedup vs baseline: 1.1614x; 1.1614x over previous
//
#include <hip/hip_runtime.h>

#define BB   2048
#define NNX  64
#define DD   256
#define KKC  32
#define LLN  2
#define HHN  8
#define DHH  32
#define DFFN 1024
#define BNT  (BB*NNX)   // 131072

typedef short s16x8 __attribute__((ext_vector_type(8)));
typedef float f32x4 __attribute__((ext_vector_type(4)));

#define GLOAD_LDS16(gp, lp) __builtin_amdgcn_global_load_lds( \
    (const __attribute__((address_space(1))) void*)(gp),      \
    (__attribute__((address_space(3))) void*)(lp), 16, 0, 0)

#define WAITVM4() asm volatile("s_waitcnt vmcnt(4)" ::: "memory")
#define WAITVM0() asm volatile("s_waitcnt vmcnt(0)" ::: "memory")
#define WAITLGKM0() do { asm volatile("s_waitcnt lgkmcnt(0)" ::: "memory"); \
                         __builtin_amdgcn_sched_barrier(0); } while (0)
#define SBAR() __builtin_amdgcn_s_barrier()

__device__ __forceinline__ unsigned short f2bf(float f) {
  unsigned int u = __float_as_uint(f);
  u += 0x7fffu + ((u >> 16) & 1u);   // RNE
  return (unsigned short)(u >> 16);
}
__device__ __forceinline__ float bf2f(unsigned short u) {
  return __uint_as_float(((unsigned int)u) << 16);
}

// f32 -> fp8 e4m3fn (OCP), input must be >= 0 and <= 448
__device__ __forceinline__ unsigned char f2fp8(float f) {
  unsigned u = __float_as_uint(f);
  unsigned lsb = (u >> 20) & 1u;
  u += 0x7FFFFu + lsb;                 // RNE at mantissa bit 20
  int e = (int)((u >> 23) & 255u) - 120;
  if (e <= 0) {                        // subnormal: units of 2^-9
    int q = (int)(f * 512.f + 0.5f);   // q in [0,8]; 8 rolls into first normal
    return (unsigned char)q;
  }
  if (e > 15) return 0x7E;             // clamp to 448
  return (unsigned char)((e << 3) | ((u >> 20) & 7u));
}
__device__ __forceinline__ unsigned char f2fp8s(float f) {  // signed
  unsigned s = __float_as_uint(f) >> 31;
  float a = fminf(fabsf(f), 448.f);
  return (unsigned char)((s << 7) | f2fp8(a));
}

// ---------------- f32 -> bf16 bulk convert (input) ----------------
__global__ __launch_bounds__(256) void cvt_kernel(const float4* __restrict__ src,
                                                  ushort4* __restrict__ dst, int n4) {
  int i = blockIdx.x * 256 + threadIdx.x;
  int st = gridDim.x * 256;
  for (; i < n4; i += st) {
    float4 v = src[i];
    ushort4 o;
    o.x = f2bf(v.x); o.y = f2bf(v.y); o.z = f2bf(v.z); o.w = f2bf(v.w);
    dst[i] = o;
  }
}

// -------- all-weights convert: wq/wo/w1 -> bf16; w2 -> fp8 e4m3 (x64) --------
__global__ __launch_bounds__(256) void cvtw_kernel(const float4* __restrict__ wq, ushort4* __restrict__ dq,
                                                   const float4* __restrict__ wo, ushort4* __restrict__ dov,
                                                   const float4* __restrict__ w1, ushort4* __restrict__ d1,
                                                   const float4* __restrict__ w2, uchar4* __restrict__ d2) {
  const int n0 = 98304, n1 = 32768, n2 = 131072, n3 = 131072;  // float4 counts
  int i = blockIdx.x * 256 + threadIdx.x;
  int st = gridDim.x * 256;
  for (; i < n0 + n1 + n2 + n3; i += st) {
    int j = i;
    if (j < n0) {
      float4 v = wq[j];
      dq[j] = (ushort4){f2bf(v.x), f2bf(v.y), f2bf(v.z), f2bf(v.w)};
    } else if ((j -= n0) < n1) {
      float4 v = wo[j];
      dov[j] = (ushort4){f2bf(v.x), f2bf(v.y), f2bf(v.z), f2bf(v.w)};
    } else if ((j -= n1) < n2) {
      float4 v = w1[j];
      d1[j] = (ushort4){f2bf(v.x), f2bf(v.y), f2bf(v.z), f2bf(v.w)};
    } else {
      j -= n2;
      float4 v = w2[j];
      d2[j] = (uchar4){f2fp8s(v.x * 64.f), f2fp8s(v.y * 64.f),
                       f2fp8s(v.z * 64.f), f2fp8s(v.w * 64.f)};
    }
  }
}

// -------- tanh(mu) table: bf16 [32][264] (padded) + |mt|^2 f32 --------
__global__ void mt_kernel(const float* __restrict__ mus, unsigned short* __restrict__ mtb,
                          float* __restrict__ mtn) {
  int k = threadIdx.x;
  if (k < 32) {
    float acc = 0.f;
    for (int d = 0; d < 256; d++) {
      float t = tanhf(mus[k * 256 + d]);
      mtb[k * 264 + d] = f2bf(t);
      acc += t * t;
    }
    mtn[k] = acc;
  }
}

// ---------------- prob_pi, prob_A, zero entropy ----------------
__global__ void piA_kernel(const float* __restrict__ il, const float* __restrict__ tl,
                           float* __restrict__ d_pi, float* __restrict__ d_A,
                           float* __restrict__ d_ent) {
  int lane = threadIdx.x;
  if (lane == 0) *d_ent = 0.f;
  if (lane < 32) {
    float v = il[lane];
    float mx = v;
    #pragma unroll
    for (int off = 16; off; off >>= 1) mx = fmaxf(mx, __shfl_xor(mx, off, 32));
    float e = expf(v - mx), sm = e;
    #pragma unroll
    for (int off = 16; off; off >>= 1) sm += __shfl_xor(sm, off, 32);
    d_pi[lane] = e / sm;
    for (int r = 0; r < 32; r++) {
      float a = tl[r * 32 + lane];
      float m2 = a;
      #pragma unroll
      for (int off = 16; off; off >>= 1) m2 = fmaxf(m2, __shfl_xor(m2, off, 32));
      float e2 = expf(a - m2), s2 = e2;
      #pragma unroll
      for (int off = 16; off; off >>= 1) s2 += __shfl_xor(s2, off, 32);
      d_A[r * 32 + lane] = e2 / s2;
    }
  }
}

// ======== 128x128 tile, BK=32, 4-wave, counted-vmcnt pipelined NT GEMM ========
// (R7-proven structure) EPI 0: bf16 out; 1: relu -> fp8 e4m3 (x8 scale).
template <int EPI>
__global__ __launch_bounds__(256, 4) void gemm_nt(const unsigned short* __restrict__ A,
                                                  const unsigned short* __restrict__ Bw,
                                                  const float* __restrict__ bias,
                                                  void* __restrict__ outp,
                                                  int N, int K, int nx) {
  __shared__ unsigned short lds[16384];   // 32 KB: [2 buf][A 4096 | B 4096]
  const int t = threadIdx.x;
  const int bid = blockIdx.x, nwg = gridDim.x;
  const int wg = (bid & 7) * (nwg >> 3) + (bid >> 3);   // nwg % 8 == 0
  const int m0 = (wg / nx) << 7;
  const int n0 = (wg % nx) << 7;
  const int lane = t & 63, w = t >> 6;
  const int wm = w >> 1, wn = w & 1;      // 2x2 waves, wave tile 64x64
  const int lr = lane & 15, lk = lane >> 4;

  const int r0 = t >> 2, sg = t & 3;
  const int s0 = sg ^ ((r0 >> 1) & 3);
  const int r1 = r0 + 64;
  const int s1 = sg ^ ((r1 >> 1) & 3);
  const int aoff0 = (m0 + r0) * K + s0 * 8;
  const int aoff1 = (m0 + r1) * K + s1 * 8;
  const int boff0 = (n0 + r0) * K + s0 * 8;
  const int boff1 = (n0 + r1) * K + s1 * 8;

#define STAGE(buf, k0) do {                                    \
    char* la = (char*)lds + (buf) * 16384;                     \
    GLOAD_LDS16(A + aoff0 + (k0), la + t * 16);                \
    GLOAD_LDS16(A + aoff1 + (k0), la + 4096 + t * 16);         \
    GLOAD_LDS16(Bw + boff0 + (k0), la + 8192 + t * 16);        \
    GLOAD_LDS16(Bw + boff1 + (k0), la + 12288 + t * 16);       \
  } while (0)

  f32x4 acc[4][4];
  #pragma unroll
  for (int i = 0; i < 4; i++)
    #pragma unroll
    for (int j = 0; j < 4; j++) acc[i][j] = (f32x4)(0.f);

  const int ra = wm * 64 + lr, rb = wn * 64 + lr;
  const int sla = lk ^ ((ra >> 1) & 3), slb = lk ^ ((rb >> 1) & 3);

  const int NT = K >> 5;
  STAGE(0, 0);
  STAGE(1, 32);
  WAITVM4();
  SBAR();

  int c = 0;
  for (int kt = 0; kt < NT; kt++) {
    s16x8 af[4], bf[4];
    {
      const unsigned short* ua = lds + c * 8192;
      const unsigned short* ub = ua + 4096;
      #pragma unroll
      for (int mf = 0; mf < 4; mf++)
        af[mf] = *(const s16x8*)&ua[(ra + mf * 16) * 32 + sla * 8];
      #pragma unroll
      for (int nf = 0; nf < 4; nf++)
        bf[nf] = *(const s16x8*)&ub[(rb + nf * 16) * 32 + slb * 8];
    }
    __builtin_amdgcn_s_setprio(1);
    #pragma unroll
    for (int mf = 0; mf < 4; mf++)
      #pragma unroll
      for (int nf = 0; nf < 4; nf++)
        acc[mf][nf] = __builtin_amdgcn_mfma_f32_16x16x32_bf16(af[mf], bf[nf], acc[mf][nf], 0, 0, 0);
    __builtin_amdgcn_s_setprio(0);
    SBAR();
    if (kt < NT - 2) {
      STAGE(c, (kt + 2) << 5);
      WAITVM4();
    } else if (kt == NT - 2) {
      WAITVM0();
    }
    SBAR();
    c ^= 1;
  }
#undef STAGE

  #pragma unroll
  for (int nf = 0; nf < 4; nf++) {
    int col = n0 + wn * 64 + nf * 16 + lr;
    float bv = bias[col];
    #pragma unroll
    for (int mf = 0; mf < 4; mf++)
      #pragma unroll
      for (int r = 0; r < 4; r++) {
        int row = m0 + wm * 64 + mf * 16 + lk * 4 + r;
        size_t o = (size_t)row * N + col;
        float v = acc[mf][nf][r] + bv;
        if (EPI == 0) {
          ((unsigned short*)outp)[o] = f2bf(v);
        } else {
          float h = fminf(fmaxf(v, 0.f) * 8.f, 448.f);
          ((unsigned char*)outp)[o] = f2fp8(h);
        }
      }
  }
}

// ------- GEMM (BM=128, BN=256 full width) + bias + residual + LayerNorm -------
// (R4-measured bf16 version; used for the Wo projection, K=256)
template <bool WR32>
__global__ __launch_bounds__(512) void gemm_ln(const unsigned short* __restrict__ A,
                                               const unsigned short* __restrict__ Bw,
                                               const float* __restrict__ bias,
                                               const unsigned short* __restrict__ res,
                                               const float* __restrict__ g,
                                               const float* __restrict__ bta,
                                               unsigned short* __restrict__ xb,
                                               float* __restrict__ x32,
                                               int K) {
  __shared__ unsigned short As[128 * 64];
  __shared__ unsigned short Bs[256 * 64];
  __shared__ float stats[2][128][4];
  const int t = threadIdx.x;
  const int nwg = gridDim.x;
  const int bid = blockIdx.x;
  const int wg = (bid & 7) * (nwg >> 3) + (bid >> 3);
  const int m0 = wg << 7;

  const int lane = t & 63, w = t >> 6;
  const int wm = w >> 2, wn = w & 3;
  const int lr = lane & 15, lk = lane >> 4;

  size_t aoff[2], boff[4];
  #pragma unroll
  for (int p = 0; p < 2; p++) {
    int u = p * 512 + t;
    int row = u >> 3, sp = u & 7;
    int seg = sp ^ (((row >> 2) & 1) << 1);
    aoff[p] = (size_t)(m0 + row) * K + seg * 8;
  }
  #pragma unroll
  for (int p = 0; p < 4; p++) {
    int u = p * 512 + t;
    int row = u >> 3, sp = u & 7;
    int seg = sp ^ (((row >> 2) & 1) << 1);
    boff[p] = (size_t)row * K + seg * 8;
  }

  f32x4 acc[4][4];
  #pragma unroll
  for (int i = 0; i < 4; i++)
    #pragma unroll
    for (int j = 0; j < 4; j++) acc[i][j] = (f32x4)(0.f);

  for (int k0 = 0; k0 < K; k0 += 64) {
    #pragma unroll
    for (int p = 0; p < 2; p++)
      GLOAD_LDS16(A + aoff[p] + k0, (char*)As + (p * 512 + t) * 16);
    #pragma unroll
    for (int p = 0; p < 4; p++)
      GLOAD_LDS16(Bw + boff[p] + k0, (char*)Bs + (p * 512 + t) * 16);
    __syncthreads();
    #pragma unroll
    for (int z = 0; z < 2; z++) {
      s16x8 af[4], bfr[4];
      #pragma unroll
      for (int mf = 0; mf < 4; mf++) {
        int row = wm * 64 + mf * 16 + lr;
        int cc = (z * 4 + lk) ^ (((row >> 2) & 1) << 1);
        af[mf] = *(const s16x8*)&As[row * 64 + cc * 8];
      }
      #pragma unroll
      for (int nf = 0; nf < 4; nf++) {
        int row = wn * 64 + nf * 16 + lr;
        int cc = (z * 4 + lk) ^ (((row >> 2) & 1) << 1);
        bfr[nf] = *(const s16x8*)&Bs[row * 64 + cc * 8];
      }
      #pragma unroll
      for (int mf = 0; mf < 4; mf++)
        #pragma unroll
        for (int nf = 0; nf < 4; nf++)
          acc[mf][nf] = __builtin_amdgcn_mfma_f32_16x16x32_bf16(af[mf], bfr[nf], acc[mf][nf], 0, 0, 0);
    }
    __syncthreads();
  }

  float bv[4];
  #pragma unroll
  for (int nf = 0; nf < 4; nf++) bv[nf] = bias[wn * 64 + nf * 16 + lr];

  #pragma unroll
  for (int mf = 0; mf < 4; mf++) {
    #pragma unroll
    for (int r = 0; r < 4; r++) {
      int grow = m0 + wm * 64 + mf * 16 + lk * 4 + r;
      float s = 0.f, q = 0.f;
      #pragma unroll
      for (int nf = 0; nf < 4; nf++) {
        int col = wn * 64 + nf * 16 + lr;
        float v = acc[mf][nf][r] + bv[nf] + bf2f(res[(size_t)grow * 256 + col]);
        acc[mf][nf][r] = v;
        s += v; q += v * v;
      }
      #pragma unroll
      for (int off = 1; off < 16; off <<= 1) { s += __shfl_xor(s, off); q += __shfl_xor(q, off); }
      if (lr == 0) {
        int lrow = wm * 64 + mf * 16 + lk * 4 + r;
        stats[0][lrow][wn] = s;
        stats[1][lrow][wn] = q;
      }
    }
  }
  __syncthreads();

  float gv[4], bbv[4];
  #pragma unroll
  for (int nf = 0; nf < 4; nf++) {
    int col = wn * 64 + nf * 16 + lr;
    gv[nf] = g[col]; bbv[nf] = bta[col];
  }
  #pragma unroll
  for (int mf = 0; mf < 4; mf++) {
    #pragma unroll
    for (int r = 0; r < 4; r++) {
      int lrow = wm * 64 + mf * 16 + lk * 4 + r;
      int grow = m0 + lrow;
      float s4 = stats[0][lrow][0] + stats[0][lrow][1] + stats[0][lrow][2] + stats[0][lrow][3];
      float q4 = stats[1][lrow][0] + stats[1][lrow][1] + stats[1][lrow][2] + stats[1][lrow][3];
      float mean = s4 * (1.f / 256.f);
      float var = q4 * (1.f / 256.f) - mean * mean;
      float rs = rsqrtf(var + 1e-5f);
      #pragma unroll
      for (int nf = 0; nf < 4; nf++) {
        int col = wn * 64 + nf * 16 + lr;
        float val = (acc[mf][nf][r] - mean) * rs * gv[nf] + bbv[nf];
        xb[(size_t)grow * 256 + col] = f2bf(val);
        if (WR32) x32[(size_t)grow * 256 + col] = val;
      }
    }
  }
}

// ---- fp8 GEMM (BM=128, BN=256 full width) + bias + residual + LayerNorm ----
// A = h fp8 (x8), B = W2 fp8 (x64); acc rescaled by 1/512.
// LDS layout: A [2 units][128 rows][32 B] then B [2 units][256 rows][32 B].
// Staging dst is LINEAR (la + idx*16, wave-uniform-base rule); the global
// SOURCE is per-lane permuted to match: idx -> (unit, row, 16B seg).
template <bool WR32>
__global__ __launch_bounds__(512) void gemm_ln_fp8(const unsigned char* __restrict__ A,
                                                   const unsigned char* __restrict__ Bw,
                                                   const float* __restrict__ bias,
                                                   const unsigned short* __restrict__ res,
                                                   const float* __restrict__ g,
                                                   const float* __restrict__ bta,
                                                   unsigned short* __restrict__ xb,
                                                   float* __restrict__ x32,
                                                   int K) {
  __shared__ unsigned char lds8[24576];   // A 8192 B | B 16384 B
  float* stats = (float*)lds8;            // 4 KB, post-loop only
  const int t = threadIdx.x;
  const int nwg = gridDim.x;
  const int bid = blockIdx.x;
  const int wg = (bid & 7) * (nwg >> 3) + (bid >> 3);
  const int m0 = wg << 7;

  const int lane = t & 63, w = t >> 6;
  const int wm = w >> 2, wn = w & 3;
  const int lr = lane & 15, lk = lane >> 4;

  // A: idx t in [0,512) -> unit t>>8, row (t>>1)&127, seg t&1
  const int auu = t >> 8, arow = (t >> 1) & 127, asg = t & 1;
  const size_t aoff = (size_t)(m0 + arow) * K + auu * 32 + asg * 16;
  // B: idx p*512+t in [0,1024) -> unit idx>>9, row (idx>>1)&255, seg idx&1
  size_t boff[2];
  #pragma unroll
  for (int p = 0; p < 2; p++) {
    int idx = p * 512 + t;
    int buu = idx >> 9, brow = (idx >> 1) & 255, bsg = idx & 1;
    boff[p] = (size_t)brow * K + buu * 32 + bsg * 16;
  }

  f32x4 acc[4][4];
  #pragma unroll
  for (int i = 0; i < 4; i++)
    #pragma unroll
    for (int j = 0; j < 4; j++) acc[i][j] = (f32x4)(0.f);

  for (int k0 = 0; k0 < K; k0 += 64) {
    GLOAD_LDS16(A + aoff + k0, (char*)lds8 + t * 16);
    GLOAD_LDS16(Bw + boff[0] + k0, (char*)lds8 + 8192 + t * 16);
    GLOAD_LDS16(Bw + boff[1] + k0, (char*)lds8 + 16384 + t * 16);
    __syncthreads();
    #pragma unroll
    for (int kk = 0; kk < 2; kk++) {
      long long af[4], bf[4];
      #pragma unroll
      for (int mf = 0; mf < 4; mf++)
        af[mf] = *(const long long*)&lds8[kk * 4096 + (wm * 64 + mf * 16 + lr) * 32 + lk * 8];
      #pragma unroll
      for (int nf = 0; nf < 4; nf++)
        bf[nf] = *(const long long*)&lds8[8192 + kk * 8192 + (wn * 64 + nf * 16 + lr) * 32 + lk * 8];
      #pragma unroll
      for (int mf = 0; mf < 4; mf++)
        #pragma unroll
        for (int nf = 0; nf < 4; nf++)
          acc[mf][nf] = __builtin_amdgcn_mfma_f32_16x16x32_fp8_fp8(af[mf], bf[nf], acc[mf][nf], 0, 0, 0);
    }
    __syncthreads();
  }

  const float isc = 1.f / 512.f;   // undo h x8 and W2 x64
  float bv[4];
  #pragma unroll
  for (int nf = 0; nf < 4; nf++) bv[nf] = bias[wn * 64 + nf * 16 + lr];

  #pragma unroll
  for (int mf = 0; mf < 4; mf++) {
    #pragma unroll
    for (int r = 0; r < 4; r++) {
      int grow = m0 + wm * 64 + mf * 16 + lk * 4 + r;
      float s = 0.f, q = 0.f;
      #pragma unroll
      for (int nf = 0; nf < 4; nf++) {
        int col = wn * 64 + nf * 16 + lr;
        float v = acc[mf][nf][r] * isc + bv[nf] + bf2f(res[(size_t)grow * 256 + col]);
        acc[mf][nf][r] = v;
        s += v; q += v * v;
      }
      #pragma unroll
      for (int off = 1; off < 16; off <<= 1) { s += __shfl_xor(s, off); q += __shfl_xor(q, off); }
      if (lr == 0) {
        int lrow = wm * 64 + mf * 16 + lk * 4 + r;
        stats[lrow * 4 + wn] = s;
        stats[512 + lrow * 4 + wn] = q;
      }
    }
  }
  __syncthreads();

  float gv[4], bbv[4];
  #pragma unroll
  for (int nf = 0; nf < 4; nf++) {
    int col = wn * 64 + nf * 16 + lr;
    gv[nf] = g[col]; bbv[nf] = bta[col];
  }
  #pragma unroll
  for (int mf = 0; mf < 4; mf++) {
    #pragma unroll
    for (int r = 0; r < 4; r++) {
      int lrow = wm * 64 + mf * 16 + lk * 4 + r;
      int grow = m0 + lrow;
      float s4 = stats[lrow * 4 + 0] + stats[lrow * 4 + 1] + stats[lrow * 4 + 2] + stats[lrow * 4 + 3];
      float q4 = stats[512 + lrow * 4 + 0] + stats[512 + lrow * 4 + 1]
               + stats[512 + lrow * 4 + 2] + stats[512 + lrow * 4 + 3];
      float mean = s4 * (1.f / 256.f);
      float var = q4 * (1.f / 256.f) - mean * mean;
      float rs = rsqrtf(var + 1e-5f);
      #pragma unroll
      for (int nf = 0; nf < 4; nf++) {
        int col = wn * 64 + nf * 16 + lr;
        float val = (acc[mf][nf][r] - mean) * rs * gv[nf] + bbv[nf];
        xb[(size_t)grow * 256 + col] = f2bf(val);
        if (WR32) x32[(size_t)grow * 256 + col] = val;
      }
    }
  }
}

// ---------------- attention: one wave per (b,h), compact LDS, V^T ----------
// (R11-proven, unchanged)
__global__ __launch_bounds__(64) void attn_kernel(const unsigned short* __restrict__ qkv,
                                                  unsigned short* __restrict__ ob) {
  __shared__ unsigned short al[6784];   // 13568 B
  unsigned short* qs = al;
  unsigned short* ks = al + 2048;
  unsigned short* vs = al + 4608;
  unsigned short* vt = al;              // [32][68]
  unsigned short* ps = al + 2176;       // [64][72]
  const int bh = blockIdx.x;
  const int b = bh >> 3, h = bh & 7;
  const int lane = threadIdx.x;
  const int lr = lane & 15, lk = lane >> 4;

  #pragma unroll
  for (int p = 0; p < 4; p++) {
    int u = lane + p * 64;
    int row = u >> 2, seg = u & 3;
    size_t gb = (size_t)(b * 64 + row) * 768 + h * 32 + seg * 8;
    GLOAD_LDS16(qkv + gb, (char*)al + u * 16);
    GLOAD_LDS16(qkv + gb + 256, (char*)al + 4096 + u * 16);
    GLOAD_LDS16(qkv + gb + 512, (char*)al + 9216 + u * 16);
  }
  __syncthreads();

  s16x8 aq[4], bk[4], vchunk[4];
  #pragma unroll
  for (int mi = 0; mi < 4; mi++) aq[mi] = *(const s16x8*)&qs[(mi * 16 + lr) * 32 + lk * 8];
  #pragma unroll
  for (int nj = 0; nj < 4; nj++) bk[nj] = *(const s16x8*)&ks[(nj * 16 + lr) * 32 + lk * 8];
  const int vrow = lane >> 2, vcs = (lane & 3) * 8;
  #pragma unroll
  for (int q = 0; q < 4; q++)
    vchunk[q] = *(const s16x8*)&vs[(q * 16 + vrow) * 32 + vcs];
  WAITLGKM0();

  #pragma unroll
  for (int q = 0; q < 4; q++)
    #pragma unroll
    for (int j = 0; j < 8; j++)
      vt[(vcs + j) * 68 + q * 16 + vrow] = (unsigned short)vchunk[q][j];

  f32x4 s[4][4];
  #pragma unroll
  for (int i = 0; i < 4; i++)
    #pragma unroll
    for (int j = 0; j < 4; j++) s[i][j] = (f32x4)(0.f);
  #pragma unroll
  for (int mi = 0; mi < 4; mi++)
    #pragma unroll
    for (int nj = 0; nj < 4; nj++)
      s[mi][nj] = __builtin_amdgcn_mfma_f32_16x16x32_bf16(aq[mi], bk[nj], s[mi][nj], 0, 0, 0);

  const float scale = 0.17677669529663687f;
  #pragma unroll
  for (int mi = 0; mi < 4; mi++) {
    #pragma unroll
    for (int r = 0; r < 4; r++) {
      float t0 = s[mi][0][r] * scale, t1 = s[mi][1][r] * scale;
      float t2 = s[mi][2][r] * scale, t3 = s[mi][3][r] * scale;
      float mx = fmaxf(fmaxf(t0, t1), fmaxf(t2, t3));
      #pragma unroll
      for (int off = 8; off; off >>= 1) mx = fmaxf(mx, __shfl_xor(mx, off, 16));
      float e0 = expf(t0 - mx), e1 = expf(t1 - mx), e2 = expf(t2 - mx), e3 = expf(t3 - mx);
      float sm = e0 + e1 + e2 + e3;
      #pragma unroll
      for (int off = 8; off; off >>= 1) sm += __shfl_xor(sm, off, 16);
      float inv = 1.f / sm;
      int prow = mi * 16 + lk * 4 + r;
      ps[prow * 72 + lr + 0]  = f2bf(e0 * inv);
      ps[prow * 72 + lr + 16] = f2bf(e1 * inv);
      ps[prow * 72 + lr + 32] = f2bf(e2 * inv);
      ps[prow * 72 + lr + 48] = f2bf(e3 * inv);
    }
  }
  WAITLGKM0();

  f32x4 oacc[4][2];
  #pragma unroll
  for (int i = 0; i < 4; i++) { oacc[i][0] = (f32x4)(0.f); oacc[i][1] = (f32x4)(0.f); }
  #pragma unroll
  for (int kk = 0; kk < 2; kk++) {
    s16x8 bv[2];
    #pragma unroll
    for (int nf = 0; nf < 2; nf++)
      bv[nf] = *(const s16x8*)&vt[(nf * 16 + lr) * 68 + kk * 32 + lk * 8];
    #pragma unroll
    for (int mi = 0; mi < 4; mi++) {
      s16x8 ap = *(const s16x8*)&ps[(mi * 16 + lr) * 72 + kk * 32 + lk * 8];
      #pragma unroll
      for (int nf = 0; nf < 2; nf++)
        oacc[mi][nf] = __builtin_amdgcn_mfma_f32_16x16x32_bf16(ap, bv[nf], oacc[mi][nf], 0, 0, 0);
    }
  }
  #pragma unroll
  for (int mi = 0; mi < 4; mi++)
    #pragma unroll
    for (int nf = 0; nf < 2; nf++)
      #pragma unroll
      for (int r = 0; r < 4; r++) {
        int tok = mi * 16 + lk * 4 + r;
        int c = nf * 16 + lr;
        ob[(size_t)(b * 64 + tok) * 256 + h * 32 + c] = f2bf(oacc[mi][nf][r]);
      }
}

// -------- cluster probs -> log_emit via MFMA (R12-proven, unchanged) --------
__global__ __launch_bounds__(256) void cluster_kernel(const unsigned short* __restrict__ xb,
                                                      const unsigned short* __restrict__ mtb,
                                                      const float* __restrict__ mtn,
                                                      float* __restrict__ log_emit) {
  __shared__ unsigned short ms[32 * 264];   // 16.5 KB
  const int t = threadIdx.x;
  for (int i = t; i < 2112; i += 256)
    ((uint2*)ms)[i] = ((const uint2*)mtb)[i];
  const int lane = t & 63, w = t >> 6;
  const int lr = lane & 15, lk = lane >> 4;
  const float mtn0 = mtn[lr], mtn1 = mtn[16 + lr];
  __syncthreads();

  const size_t tok0 = (size_t)blockIdx.x * 256 + (size_t)w * 64;
  f32x4 s[4][2];
  #pragma unroll
  for (int i = 0; i < 4; i++) { s[i][0] = (f32x4)(0.f); s[i][1] = (f32x4)(0.f); }

  #pragma unroll
  for (int kk = 0; kk < 8; kk++) {
    s16x8 bf0 = *(const s16x8*)&ms[lr * 264 + lk * 8 + kk * 32];
    s16x8 bf1 = *(const s16x8*)&ms[(16 + lr) * 264 + lk * 8 + kk * 32];
    #pragma unroll
    for (int mi = 0; mi < 4; mi++) {
      s16x8 af = *(const s16x8*)&xb[(tok0 + mi * 16 + lr) * 256 + lk * 8 + kk * 32];
      s[mi][0] = __builtin_amdgcn_mfma_f32_16x16x32_bf16(af, bf0, s[mi][0], 0, 0, 0);
      s[mi][1] = __builtin_amdgcn_mfma_f32_16x16x32_bf16(af, bf1, s[mi][1], 0, 0, 0);
    }
  }

  #pragma unroll
  for (int mi = 0; mi < 4; mi++) {
    #pragma unroll
    for (int r = 0; r < 4; r++) {
      float l0 = (2.f * s[mi][0][r] - mtn0) * 0.1f;
      float l1 = (2.f * s[mi][1][r] - mtn1) * 0.1f;
      float mx = fmaxf(l0, l1);
      #pragma unroll
      for (int off = 8; off; off >>= 1) mx = fmaxf(mx, __shfl_xor(mx, off, 16));
      float e0 = expf(l0 - mx), e1 = expf(l1 - mx);
      float sm = e0 + e1;
      #pragma unroll
      for (int off = 8; off; off >>= 1) sm += __shfl_xor(sm, off, 16);
      float inv = 1.f / sm;
      size_t row = tok0 + mi * 16 + lk * 4 + r;
      log_emit[row * 32 + lr]      = logf(e0 * inv + 1e-10f);
      log_emit[row * 32 + 16 + lr] = logf(e1 * inv + 1e-10f);
    }
  }
}

// ---------------- HMM forward scan + entropy ----------------
__global__ __launch_bounds__(256) void scan_kernel(const float* __restrict__ log_emit,
                                                   const float* __restrict__ pi,
                                                   const float* __restrict__ A,
                                                   float* __restrict__ cp,
                                                   float* __restrict__ ent) {
  const int g = threadIdx.x >> 5, j = threadIdx.x & 31;
  const int batch = blockIdx.x * 8 + g;
  float regA[32];
  #pragma unroll
  for (int i = 0; i < 32; i++) regA[i] = A[i * 32 + j];
  const float* le = log_emit + (size_t)batch * 64 * 32;
  float* cpo = cp + (size_t)batch * 64 * 32;

  float u = logf(pi[j] + 1e-10f) + le[j];
  float mx = u;
  #pragma unroll
  for (int off = 16; off; off >>= 1) mx = fmaxf(mx, __shfl_xor(mx, off, 32));
  float e = expf(u - mx), sm = e;
  #pragma unroll
  for (int off = 16; off; off >>= 1) sm += __shfl_xor(sm, off, 32);
  float p = e / sm;
  cpo[j] = p;
  float enta = p * logf(p + 1e-10f);

  for (int n = 1; n < 64; n++) {
    float tt = 0.f;
    #pragma unroll
    for (int i = 0; i < 32; i++) tt += __shfl(p, i, 32) * regA[i];
    u = logf(tt + 1e-10f) + le[n * 32 + j];
    mx = u;
    #pragma unroll
    for (int off = 16; off; off >>= 1) mx = fmaxf(mx, __shfl_xor(mx, off, 32));
    e = expf(u - mx); sm = e;
    #pragma unroll
    for (int off = 16; off; off >>= 1) sm += __shfl_xor(sm, off, 32);
    p = e / sm;
    cpo[n * 32 + j] = p;
    enta += p * logf(p + 1e-10f);
  }
  #pragma unroll
  for (int off = 16; off; off >>= 1) enta += __shfl_xor(enta, off, 32);
  if (j == 0) atomicAdd(ent, -enta * (1.f / (2048.f * 64.f)));
}

// ---------------- launcher ----------------
extern "C" void kernel_launch(void* const* d_in, const int* in_sizes, int n_in,
                              void* d_out, int out_size, void* d_ws, size_t ws_size,
                              hipStream_t stream) {
  const float* input = (const float*)d_in[0];
  const float* init_logits = (const float*)d_in[1];
  const float* trans = (const float*)d_in[2];
  const float* Wqkv = (const float*)d_in[3];
  const float* bqkv = (const float*)d_in[4];
  const float* Wo = (const float*)d_in[5];
  const float* bo = (const float*)d_in[6];
  const float* ln1g = (const float*)d_in[7];
  const float* ln1b = (const float*)d_in[8];
  const float* ln2g = (const float*)d_in[9];
  const float* ln2b = (const float*)d_in[10];
  const float* W1 = (const float*)d_in[11];
  const float* b1 = (const float*)d_in[12];
  const float* W2 = (const float*)d_in[13];
  const float* b2 = (const float*)d_in[14];
  const float* mus = (const float*)d_in[15];

  float* out = (float*)d_out;
  float* cp = out;                  // [BN,32]
  float* x = out + 4194304;         // emb_all [BN,256] f32
  float* d_pi = out + 37748736;
  float* d_A = out + 37748768;
  float* d_ent = out + 37749792;

  char* ws = (char*)d_ws;
  unsigned short* qkv = (unsigned short*)ws;        // region A: qkv -> hb(fp8) -> log_emit
  unsigned char* hb = (unsigned char*)ws;           // [BN][1024] fp8, 128 MB
  float* log_emit = (float*)ws;
  unsigned short* ob = (unsigned short*)(ws + 268435456ull);   // region B: attn out
  unsigned short* xb = (unsigned short*)(ws + 335544320ull);   // residual stream bf16
  unsigned short* wq_b = (unsigned short*)(ws + 402653184ull);
  unsigned short* wo_b = (unsigned short*)(ws + 402653184ull + 786432ull);
  unsigned short* w1_b = (unsigned short*)(ws + 402653184ull + 1048576ull);
  unsigned char* w2_f = (unsigned char*)(ws + 402653184ull + 2097152ull);   // fp8 x64
  unsigned short* mtb = (unsigned short*)(ws + 402653184ull + 3145728ull);
  float* mtn = (float*)(ws + 402653184ull + 3178496ull);

  cvt_kernel<<<2048, 256, 0, stream>>>((const float4*)input, (ushort4*)xb, BNT * 256 / 4);
  cvtw_kernel<<<512, 256, 0, stream>>>((const float4*)Wqkv, (ushort4*)wq_b,
                                       (const float4*)Wo, (ushort4*)wo_b,
                                       (const float4*)W1, (ushort4*)w1_b,
                                       (const float4*)W2, (uchar4*)w2_f);
  mt_kernel<<<1, 64, 0, stream>>>(mus, mtb, mtn);
  piA_kernel<<<1, 64, 0, stream>>>(init_logits, trans, d_pi, d_A, d_ent);

  for (int l = 0; l < 2; l++) {
    gemm_nt<0><<<6144, 256, 0, stream>>>(xb, wq_b + l * 196608, bqkv + l * 768,
                                         qkv, 768, 256, 6);
    attn_kernel<<<16384, 64, 0, stream>>>(qkv, ob);
    gemm_ln<false><<<1024, 512, 0, stream>>>(ob, wo_b + l * 65536, bo + l * 256,
                                             xb, ln1g + l * 256, ln1b + l * 256,
                                             xb, nullptr, 256);
    gemm_nt<1><<<8192, 256, 0, stream>>>(xb, w1_b + l * 262144, b1 + l * 1024,
                                         hb, 1024, 256, 8);
    if (l == LLN - 1)
      gemm_ln_fp8<true><<<1024, 512, 0, stream>>>(hb, w2_f + l * 262144, b2 + l * 256,
                                                  xb, ln2g + l * 256, ln2b + l * 256,
                                                  xb, x, 1024);
    else
      gemm_ln_fp8<false><<<1024, 512, 0, stream>>>(hb, w2_f + l * 262144, b2 + l * 256,
                                                   xb, ln2g + l * 256, ln2b + l * 256,
                                                   xb, nullptr, 1024);
  }

  cluster_kernel<<<512, 256, 0, stream>>>(xb, mtb, mtn, log_emit);
  scan_kernel<<<256, 256, 0, stream>>>(log_emit, d_pi, d_A, cp, d_ent);
}